// Round 1
// baseline (194.790 us; speedup 1.0000x reference)
//
#include <hip/hip_runtime.h>
#include <cstdint>
#include <cstddef>

typedef _Float16 f16;
typedef __attribute__((ext_vector_type(8))) _Float16 h8v;
typedef __attribute__((ext_vector_type(4))) _Float16 h4v;
typedef __attribute__((ext_vector_type(4))) float f4v;

#define DIM 1024
#define SEQ 1024
#define NH 16
#define HD 64

// async global->LDS, 16B per lane; LDS dest = wave-uniform base + lane*16
__device__ __forceinline__ void gld16(const void* g, void* l) {
  __builtin_amdgcn_global_load_lds(
      (const __attribute__((address_space(1))) void*)g,
      (__attribute__((address_space(3))) void*)l, 16, 0, 0);
}

__device__ __forceinline__ f4v mfma16(h8v a, h8v b, f4v c) {
  return __builtin_amdgcn_mfma_f32_16x16x32_f16(a, b, c, 0, 0, 0);
}

__device__ __forceinline__ void cvt_store4(f16* dst, float4 v) {
  *(h4v*)dst = (h4v){(f16)v.x, (f16)v.y, (f16)v.z, (f16)v.w};
}

// ---------------------------------------------------------------- convert
__global__ __launch_bounds__(256) void convert_kernel(
    const float* __restrict__ x,  const float* __restrict__ Wq,
    const float* __restrict__ Wk, const float* __restrict__ Wv,
    const float* __restrict__ Wo,
    f16* __restrict__ xh, f16* __restrict__ wqkv, f16* __restrict__ woh)
{
  int i = blockIdx.x * 256 + threadIdx.x;   // 1,048,576 threads = 4M floats /4
  cvt_store4(xh + 4 * (size_t)i, ((const float4*)x)[i]);
  if (i < DIM * DIM / 4) {
    cvt_store4(wqkv + 4 * (size_t)i,               ((const float4*)Wq)[i]);
    cvt_store4(wqkv + DIM * DIM + 4 * (size_t)i,   ((const float4*)Wk)[i]);
    cvt_store4(wqkv + 2 * DIM * DIM + 4 * (size_t)i, ((const float4*)Wv)[i]);
    cvt_store4(woh + 4 * (size_t)i,                ((const float4*)Wo)[i]);
  }
}

// --------------------------------------------------------------- QKV GEMM
// C[4096,3072] = xh[4096,1024] @ wqkv[3072,1024]^T, epilogue: RoPE on Q,K.
// Q,K -> [B,H,S,64]; V -> transposed [B,H,64,S] (so PV B-frags are contiguous).
// LDS tiles stored as 16B chunks with XOR swizzle: chunk(row,kc) at
// row*4 + (kc ^ ((row>>1)&3))  -> ds_read_b128 frags are 2-way (free).
__global__ __launch_bounds__(256) void qkv_gemm(
    const f16* __restrict__ A, const f16* __restrict__ W,
    f16* __restrict__ Qh, f16* __restrict__ Kh, f16* __restrict__ Vt)
{
  __shared__ f16 lA[128 * 32];
  __shared__ f16 lB[128 * 32];
  const int m0 = blockIdx.x * 128;
  const int n0 = blockIdx.y * 128;
  const int tid = threadIdx.x;
  const int w = tid >> 6, lane = tid & 63, quad = lane >> 4, l16 = lane & 15;
  const int wm = (w >> 1) * 64, wn = (w & 1) * 64;

  // staging: chunk c -> row=c>>2, kc=(c&3)^((row>>1)&3); 2 insts for A, 2 for B
  const int c0 = tid, c1 = 256 + tid;
  const int r0 = c0 >> 2, kc0 = (c0 & 3) ^ ((r0 >> 1) & 3);
  const int r1 = c1 >> 2, kc1 = (c1 & 3) ^ ((r1 >> 1) & 3);
  const f16* gA0 = A + (size_t)(m0 + r0) * DIM + kc0 * 8;
  const f16* gA1 = A + (size_t)(m0 + r1) * DIM + kc1 * 8;
  const f16* gB0 = W + (size_t)(n0 + r0) * DIM + kc0 * 8;
  const f16* gB1 = W + (size_t)(n0 + r1) * DIM + kc1 * 8;
  f16* lA0 = &lA[(c0 & ~63) * 8];
  f16* lA1 = &lA[(c1 & ~63) * 8];
  f16* lB0 = &lB[(c0 & ~63) * 8];
  f16* lB1 = &lB[(c1 & ~63) * 8];

  // fragment LDS chunk indices (constant across K loop)
  int pA[4], pB[4];
#pragma unroll
  for (int t = 0; t < 4; ++t) {
    int r = wm + t * 16 + l16;
    pA[t] = r * 4 + (quad ^ ((r >> 1) & 3));
    int rn = wn + t * 16 + l16;
    pB[t] = rn * 4 + (quad ^ ((rn >> 1) & 3));
  }

  f4v acc[4][4] = {};
  for (int kt = 0; kt < DIM / 32; ++kt) {
    const int ko = kt * 32;
    gld16(gA0 + ko, lA0);
    gld16(gA1 + ko, lA1);
    gld16(gB0 + ko, lB0);
    gld16(gB1 + ko, lB1);
    __syncthreads();   // drains vmcnt: staged tile visible to all waves
    h8v af[4], bf[4];
#pragma unroll
    for (int t = 0; t < 4; ++t) af[t] = *(const h8v*)&lA[pA[t] * 8];
#pragma unroll
    for (int t = 0; t < 4; ++t) bf[t] = *(const h8v*)&lB[pB[t] * 8];
#pragma unroll
    for (int i = 0; i < 4; ++i)
#pragma unroll
      for (int j = 0; j < 4; ++j)
        acc[i][j] = mfma16(af[i], bf[j], acc[i][j]);
    __syncthreads();   // reads done before next stage overwrites
  }

  // epilogue. C layout: col = l16 (n), row = quad*4 + reg (m).
  if (n0 < 2 * DIM) {
    // RoPE pairs (2j, 2j+1) are adjacent lanes -> shfl_xor(.,1) is the partner.
    f16* dst = (n0 < DIM) ? Qh : Kh;
#pragma unroll
    for (int i = 0; i < 4; ++i) {
      const int mb = m0 + wm + i * 16 + quad * 4;
#pragma unroll
      for (int j = 0; j < 4; ++j) {
        const int n = n0 + wn + j * 16 + l16;
        const int d = n & (DIM - 1);
        const float fr = exp2f(-0.025952563f * (float)(d >> 1)); // theta^{-2j/D}
        const float sgn = (d & 1) ? 1.0f : -1.0f;
        const int hh = d >> 6, dd = d & 63;
#pragma unroll
        for (int r = 0; r < 4; ++r) {
          const int m = mb + r;
          const int s = m & (SEQ - 1), b = m >> 10;
          const float v = acc[i][j][r];
          const float pt = __shfl_xor(v, 1, 64);
          float sn, cs;
          __sincosf((float)s * fr, &sn, &cs);
          dst[((size_t)(b * NH + hh) * SEQ + s) * HD + dd] =
              (f16)(v * cs + sgn * pt * sn);
        }
      }
    }
  } else {
    // V: store transposed [B,H,64,S]; regs are 4 consecutive s -> 8B store
#pragma unroll
    for (int i = 0; i < 4; ++i) {
      const int mb = m0 + wm + i * 16 + quad * 4;
      const int s = mb & (SEQ - 1), b = mb >> 10;
#pragma unroll
      for (int j = 0; j < 4; ++j) {
        const int d = (n0 - 2 * DIM) + wn + j * 16 + l16;
        const int hh = d >> 6, dd = d & 63;
        h4v vv = {(f16)acc[i][j][0], (f16)acc[i][j][1],
                  (f16)acc[i][j][2], (f16)acc[i][j][3]};
        *(h4v*)&Vt[((size_t)(b * NH + hh) * HD + dd) * SEQ + s] = vv;
      }
    }
  }
}

// -------------------------------------------------------------- attention
// grid (S/64, B*H); 4 waves/block, each wave owns 16 q-rows; flash-style
// online softmax over 16 key-tiles of 64. K tile [64key][64d], V tile (from
// transposed V) [64d][64key], both XOR-swizzled 8-chunk rows.
__global__ __launch_bounds__(256) void attn_kernel(
    const f16* __restrict__ Q, const f16* __restrict__ K,
    const f16* __restrict__ V, f16* __restrict__ O)
{
  __shared__ f16 lK[64 * 64];
  __shared__ f16 lV[64 * 64];
  __shared__ f16 lP[4][16 * 72];  // per-wave P transpose buffer, +8 pad
  const int tid = threadIdx.x;
  const int w = tid >> 6, lane = tid & 63, quad = lane >> 4, l16 = lane & 15;
  const int qt = blockIdx.x, bh = blockIdx.y;
  const f16* Qb = Q + (size_t)bh * SEQ * HD;
  const f16* Kb = K + (size_t)bh * SEQ * HD;
  const f16* Vb = V + (size_t)bh * HD * SEQ;
  const int q0 = qt * 64;
  const int qrow = q0 + w * 16 + l16;

  h8v aq0 = *(const h8v*)&Qb[(size_t)qrow * HD + quad * 8];
  h8v aq1 = *(const h8v*)&Qb[(size_t)qrow * HD + quad * 8 + 32];
  aq0 = aq0 * (f16)0.125f;  // fold 1/sqrt(64) into Q
  aq1 = aq1 * (f16)0.125f;

  // staging: chunk c -> row=c>>3 (0..63 over 2 insts), kc=(c&7)^(row&7)
  const int c0 = tid, c1 = 256 + tid;
  const int r0 = c0 >> 3, kc0 = (c0 & 7) ^ (r0 & 7);
  const int r1 = c1 >> 3, kc1 = (c1 & 7) ^ (r1 & 7);
  const f16* gK0 = Kb + (size_t)r0 * HD + kc0 * 8;
  const f16* gK1 = Kb + (size_t)r1 * HD + kc1 * 8;
  const f16* gV0 = Vb + (size_t)r0 * SEQ + kc0 * 8;
  const f16* gV1 = Vb + (size_t)r1 * SEQ + kc1 * 8;
  f16* lK0 = &lK[(c0 & ~63) * 8];
  f16* lK1 = &lK[(c1 & ~63) * 8];
  f16* lV0 = &lV[(c0 & ~63) * 8];
  f16* lV1 = &lV[(c1 & ~63) * 8];

  int pbt[4][2];  // B-frag chunk idx for tile j, k-half kk (shared by K and V)
#pragma unroll
  for (int j = 0; j < 4; ++j) {
    int r = j * 16 + l16;
#pragma unroll
    for (int kk = 0; kk < 2; ++kk)
      pbt[j][kk] = r * 8 + ((quad + 4 * kk) ^ (r & 7));
  }

  float mr[4], lr[4];
  f4v accO[4] = {};
#pragma unroll
  for (int r = 0; r < 4; ++r) { mr[r] = -1e30f; lr[r] = 0.f; }

  for (int t = 0; t < SEQ / 64; ++t) {
    const int key0 = t * 64;
    __syncthreads();  // previous tile's reads done (all waves)
    gld16(gK0 + (size_t)key0 * HD, lK0);
    gld16(gK1 + (size_t)key0 * HD, lK1);
    gld16(gV0 + key0, lV0);
    gld16(gV1 + key0, lV1);
    __syncthreads();  // staged tile visible

    f4v sc[4];
#pragma unroll
    for (int j = 0; j < 4; ++j) {
      f4v z = {};
      z = mfma16(aq0, *(const h8v*)&lK[pbt[j][0] * 8], z);
      z = mfma16(aq1, *(const h8v*)&lK[pbt[j][1] * 8], z);
      sc[j] = z;  // rows quad*4+r, col key = j*16 + l16
    }
    float tmax[4];
#pragma unroll
    for (int r = 0; r < 4; ++r) {
      float tm = fmaxf(fmaxf(sc[0][r], sc[1][r]), fmaxf(sc[2][r], sc[3][r]));
#pragma unroll
      for (int off = 1; off < 16; off <<= 1)
        tm = fmaxf(tm, __shfl_xor(tm, off, 64));
      tmax[r] = tm;
    }
    float alpha[4], mnew[4];
#pragma unroll
    for (int r = 0; r < 4; ++r) {
      mnew[r] = fmaxf(mr[r], tmax[r]);
      alpha[r] = __expf(mr[r] - mnew[r]);
      mr[r] = mnew[r];
    }
    float p[4][4];
    float rs[4] = {0.f, 0.f, 0.f, 0.f};
#pragma unroll
    for (int j = 0; j < 4; ++j)
#pragma unroll
      for (int r = 0; r < 4; ++r) {
        p[j][r] = __expf(sc[j][r] - mnew[r]);
        rs[r] += p[j][r];
      }
#pragma unroll
    for (int r = 0; r < 4; ++r) {
#pragma unroll
      for (int off = 1; off < 16; off <<= 1)
        rs[r] += __shfl_xor(rs[r], off, 64);
      lr[r] = lr[r] * alpha[r] + rs[r];
    }
    f4v av = {alpha[0], alpha[1], alpha[2], alpha[3]};
#pragma unroll
    for (int j = 0; j < 4; ++j) accO[j] *= av;

    // P: C-layout -> A-layout via per-wave LDS round-trip
    f16* Pw = lP[w];
#pragma unroll
    for (int j = 0; j < 4; ++j)
#pragma unroll
      for (int r = 0; r < 4; ++r)
        Pw[(quad * 4 + r) * 72 + j * 16 + l16] = (f16)p[j][r];
    h8v pa0 = *(const h8v*)&Pw[l16 * 72 + quad * 8];
    h8v pa1 = *(const h8v*)&Pw[l16 * 72 + quad * 8 + 32];
#pragma unroll
    for (int j = 0; j < 4; ++j) {
      accO[j] = mfma16(pa0, *(const h8v*)&lV[pbt[j][0] * 8], accO[j]);
      accO[j] = mfma16(pa1, *(const h8v*)&lV[pbt[j][1] * 8], accO[j]);
    }
  }

  const int b = bh >> 4, hh = bh & 15;
  f4v inv = {1.f / lr[0], 1.f / lr[1], 1.f / lr[2], 1.f / lr[3]};
#pragma unroll
  for (int j = 0; j < 4; ++j) {
    f4v o = accO[j] * inv;
    const int d = j * 16 + l16;
#pragma unroll
    for (int r = 0; r < 4; ++r) {
      const int s = q0 + w * 16 + quad * 4 + r;
      O[(size_t)(b * SEQ + s) * DIM + hh * HD + d] = (f16)o[r];
    }
  }
}

// ---------------------------------------------------------------- out GEMM
// out[4096,1024] = Oh[4096,1024] @ woh[1024,1024]^T + bias; 64x128 tiles
__global__ __launch_bounds__(256) void out_gemm(
    const f16* __restrict__ A, const f16* __restrict__ W,
    const float* __restrict__ bias, float* __restrict__ out)
{
  __shared__ f16 lA[64 * 32];
  __shared__ f16 lB[128 * 32];
  const int m0 = blockIdx.x * 64;
  const int n0 = blockIdx.y * 128;
  const int tid = threadIdx.x;
  const int w = tid >> 6, lane = tid & 63, quad = lane >> 4, l16 = lane & 15;
  const int wm = (w >> 1) * 32, wn = (w & 1) * 64;

  const int c0 = tid, c1 = 256 + tid;
  const int rA = c0 >> 2, kcA = (c0 & 3) ^ ((rA >> 1) & 3);
  const int rB1 = c1 >> 2, kcB1 = (c1 & 3) ^ ((rB1 >> 1) & 3);
  const f16* gA  = A + (size_t)(m0 + rA) * DIM + kcA * 8;
  const f16* gB0 = W + (size_t)(n0 + rA) * DIM + kcA * 8;
  const f16* gB1 = W + (size_t)(n0 + rB1) * DIM + kcB1 * 8;
  f16* lAp  = &lA[(c0 & ~63) * 8];
  f16* lB0p = &lB[(c0 & ~63) * 8];
  f16* lB1p = &lB[(c1 & ~63) * 8];

  int pA_[2], pB_[4];
#pragma unroll
  for (int t = 0; t < 2; ++t) {
    int r = wm + t * 16 + l16;
    pA_[t] = r * 4 + (quad ^ ((r >> 1) & 3));
  }
#pragma unroll
  for (int t = 0; t < 4; ++t) {
    int rn = wn + t * 16 + l16;
    pB_[t] = rn * 4 + (quad ^ ((rn >> 1) & 3));
  }

  f4v acc[2][4] = {};
  for (int kt = 0; kt < DIM / 32; ++kt) {
    const int ko = kt * 32;
    gld16(gA + ko, lAp);
    gld16(gB0 + ko, lB0p);
    gld16(gB1 + ko, lB1p);
    __syncthreads();
    h8v af[2], bf[4];
#pragma unroll
    for (int t = 0; t < 2; ++t) af[t] = *(const h8v*)&lA[pA_[t] * 8];
#pragma unroll
    for (int t = 0; t < 4; ++t) bf[t] = *(const h8v*)&lB[pB_[t] * 8];
#pragma unroll
    for (int i = 0; i < 2; ++i)
#pragma unroll
      for (int j = 0; j < 4; ++j)
        acc[i][j] = mfma16(af[i], bf[j], acc[i][j]);
    __syncthreads();
  }

#pragma unroll
  for (int i = 0; i < 2; ++i) {
#pragma unroll
    for (int j = 0; j < 4; ++j) {
      const int n = n0 + wn + j * 16 + l16;
      const float bv = bias[n];
#pragma unroll
      for (int r = 0; r < 4; ++r) {
        const int m = m0 + wm + i * 16 + quad * 4 + r;
        out[(size_t)m * DIM + n] = acc[i][j][r] + bv;
      }
    }
  }
}

// ------------------------------------------------------------------ launch
extern "C" void kernel_launch(void* const* d_in, const int* in_sizes, int n_in,
                              void* d_out, int out_size, void* d_ws, size_t ws_size,
                              hipStream_t stream)
{
  (void)in_sizes; (void)n_in; (void)out_size; (void)ws_size;
  const float* x  = (const float*)d_in[0];
  const float* Wq = (const float*)d_in[1];
  const float* Wk = (const float*)d_in[2];
  const float* Wv = (const float*)d_in[3];
  const float* Wo = (const float*)d_in[4];
  const float* bo = (const float*)d_in[5];
  // d_in[6] = start_pos == 0 (identity KV-cache path) -> ignored
  float* out = (float*)d_out;

  char* ws = (char*)d_ws;
  const size_t MB = (size_t)1 << 20;
  f16* xh   = (f16*)(ws);             // 8 MB  [4096,1024]
  f16* wqkv = (f16*)(ws + 8  * MB);   // 6 MB  [3072,1024]
  f16* woh  = (f16*)(ws + 14 * MB);   // 2 MB  [1024,1024]
  f16* Qh   = (f16*)(ws + 16 * MB);   // 8 MB  [B,H,S,64]
  f16* Kh   = (f16*)(ws + 24 * MB);   // 8 MB  [B,H,S,64]
  f16* Vt   = (f16*)(ws + 32 * MB);   // 8 MB  [B,H,64,S]
  f16* Oh   = (f16*)(ws);             // 8 MB, reuses xh region (xh dead after qkv_gemm)

  convert_kernel<<<dim3(4096), 256, 0, stream>>>(x, Wq, Wk, Wv, Wo, xh, wqkv, woh);
  qkv_gemm<<<dim3(32, 24), 256, 0, stream>>>(xh, wqkv, Qh, Kh, Vt);
  attn_kernel<<<dim3(16, 64), 256, 0, stream>>>(Qh, Kh, Vt, Oh);
  out_gemm<<<dim3(64, 8), 256, 0, stream>>>(Oh, woh, bo, out);
}

// Round 3
// 181.028 us; speedup vs baseline: 1.0760x; 1.0760x over previous
//
#include <hip/hip_runtime.h>
#include <cstdint>
#include <cstddef>

typedef _Float16 f16;
typedef __attribute__((ext_vector_type(8))) _Float16 h8v;
typedef __attribute__((ext_vector_type(4))) _Float16 h4v;
typedef __attribute__((ext_vector_type(4))) float f4v;

#define DIM 1024
#define SEQ 1024
#define NH 16
#define HD 64

// async global->LDS, 16B per lane; LDS dest = wave-uniform base + lane*16
__device__ __forceinline__ void gld16(const void* g, void* l) {
  __builtin_amdgcn_global_load_lds(
      (const __attribute__((address_space(1))) void*)g,
      (__attribute__((address_space(3))) void*)l, 16, 0, 0);
}

__device__ __forceinline__ f4v mfma16(h8v a, h8v b, f4v c) {
  return __builtin_amdgcn_mfma_f32_16x16x32_f16(a, b, c, 0, 0, 0);
}
__device__ __forceinline__ f4v mfma16k16(h4v a, h4v b, f4v c) {
  return __builtin_amdgcn_mfma_f32_16x16x16f16(a, b, c, 0, 0, 0);
}

__device__ __forceinline__ void cvt_store4(f16* dst, float4 v) {
  *(h4v*)dst = (h4v){(f16)v.x, (f16)v.y, (f16)v.z, (f16)v.w};
}

// ---------------------------------------------------------------- convert
__global__ __launch_bounds__(256) void convert_kernel(
    const float* __restrict__ x,  const float* __restrict__ Wq,
    const float* __restrict__ Wk, const float* __restrict__ Wv,
    const float* __restrict__ Wo,
    f16* __restrict__ xh, f16* __restrict__ wqkv, f16* __restrict__ woh)
{
  int i = blockIdx.x * 256 + threadIdx.x;   // 1,048,576 threads = 4M floats /4
  cvt_store4(xh + 4 * (size_t)i, ((const float4*)x)[i]);
  if (i < DIM * DIM / 4) {
    cvt_store4(wqkv + 4 * (size_t)i,               ((const float4*)Wq)[i]);
    cvt_store4(wqkv + DIM * DIM + 4 * (size_t)i,   ((const float4*)Wk)[i]);
    cvt_store4(wqkv + 2 * DIM * DIM + 4 * (size_t)i, ((const float4*)Wv)[i]);
    cvt_store4(woh + 4 * (size_t)i,                ((const float4*)Wo)[i]);
  }
}

// --------------------------------------------------------------- QKV GEMM
// C[4096,3072] = xh[4096,1024] @ wqkv[3072,1024]^T, epilogue: RoPE on Q,K.
// Q,K -> [B,H,S,64]; V -> transposed [B,H,64,S] (so PV B-frags are contiguous).
__global__ __launch_bounds__(256) void qkv_gemm(
    const f16* __restrict__ A, const f16* __restrict__ W,
    f16* __restrict__ Qh, f16* __restrict__ Kh, f16* __restrict__ Vt)
{
  __shared__ f16 lA[128 * 32];
  __shared__ f16 lB[128 * 32];
  const int m0 = blockIdx.x * 128;
  const int n0 = blockIdx.y * 128;
  const int tid = threadIdx.x;
  const int w = tid >> 6, lane = tid & 63, quad = lane >> 4, l16 = lane & 15;
  const int wm = (w >> 1) * 64, wn = (w & 1) * 64;

  const int c0 = tid, c1 = 256 + tid;
  const int r0 = c0 >> 2, kc0 = (c0 & 3) ^ ((r0 >> 1) & 3);
  const int r1 = c1 >> 2, kc1 = (c1 & 3) ^ ((r1 >> 1) & 3);
  const f16* gA0 = A + (size_t)(m0 + r0) * DIM + kc0 * 8;
  const f16* gA1 = A + (size_t)(m0 + r1) * DIM + kc1 * 8;
  const f16* gB0 = W + (size_t)(n0 + r0) * DIM + kc0 * 8;
  const f16* gB1 = W + (size_t)(n0 + r1) * DIM + kc1 * 8;
  f16* lA0 = &lA[(c0 & ~63) * 8];
  f16* lA1 = &lA[(c1 & ~63) * 8];
  f16* lB0 = &lB[(c0 & ~63) * 8];
  f16* lB1 = &lB[(c1 & ~63) * 8];

  int pA[4], pB[4];
#pragma unroll
  for (int t = 0; t < 4; ++t) {
    int r = wm + t * 16 + l16;
    pA[t] = r * 4 + (quad ^ ((r >> 1) & 3));
    int rn = wn + t * 16 + l16;
    pB[t] = rn * 4 + (quad ^ ((rn >> 1) & 3));
  }

  f4v acc[4][4] = {};
  for (int kt = 0; kt < DIM / 32; ++kt) {
    const int ko = kt * 32;
    gld16(gA0 + ko, lA0);
    gld16(gA1 + ko, lA1);
    gld16(gB0 + ko, lB0);
    gld16(gB1 + ko, lB1);
    __syncthreads();
    h8v af[4], bf[4];
#pragma unroll
    for (int t = 0; t < 4; ++t) af[t] = *(const h8v*)&lA[pA[t] * 8];
#pragma unroll
    for (int t = 0; t < 4; ++t) bf[t] = *(const h8v*)&lB[pB[t] * 8];
#pragma unroll
    for (int i = 0; i < 4; ++i)
#pragma unroll
      for (int j = 0; j < 4; ++j)
        acc[i][j] = mfma16(af[i], bf[j], acc[i][j]);
    __syncthreads();
  }

  // epilogue. C layout: col = l16 (n), row = quad*4 + reg (m).
  if (n0 < 2 * DIM) {
    f16* dst = (n0 < DIM) ? Qh : Kh;
#pragma unroll
    for (int i = 0; i < 4; ++i) {
      const int mb = m0 + wm + i * 16 + quad * 4;
#pragma unroll
      for (int j = 0; j < 4; ++j) {
        const int n = n0 + wn + j * 16 + l16;
        const int d = n & (DIM - 1);
        const float fr = exp2f(-0.025952563f * (float)(d >> 1)); // theta^{-2j/D}
        const float sgn = (d & 1) ? 1.0f : -1.0f;
        const int hh = d >> 6, dd = d & 63;
#pragma unroll
        for (int r = 0; r < 4; ++r) {
          const int m = mb + r;
          const int s = m & (SEQ - 1), b = m >> 10;
          const float v = acc[i][j][r];
          const float pt = __shfl_xor(v, 1, 64);
          float sn, cs;
          __sincosf((float)s * fr, &sn, &cs);
          dst[((size_t)(b * NH + hh) * SEQ + s) * HD + dd] =
              (f16)(v * cs + sgn * pt * sn);
        }
      }
    }
  } else {
#pragma unroll
    for (int i = 0; i < 4; ++i) {
      const int mb = m0 + wm + i * 16 + quad * 4;
      const int s = mb & (SEQ - 1), b = mb >> 10;
#pragma unroll
      for (int j = 0; j < 4; ++j) {
        const int d = (n0 - 2 * DIM) + wn + j * 16 + l16;
        const int hh = d >> 6, dd = d & 63;
        h4v vv = {(f16)acc[i][j][0], (f16)acc[i][j][1],
                  (f16)acc[i][j][2], (f16)acc[i][j][3]};
        *(h4v*)&Vt[((size_t)(b * NH + hh) * HD + dd) * SEQ + s] = vv;
      }
    }
  }
}

// -------------------------------------------------------------- attention
// Transposed-score scheme: S^T = K·Q^T so each lane owns ONE q (l16) with its
// 16 scores per 64-key tile in registers. Softmax = in-lane reduce + 2 cross-
// quad shuffles. P lands directly in the 16x16x16 A-frag layout -> PV needs
// no LDS transpose. O accumulator: C[m=q][n=d] (row = quad*4+r = q).
__global__ __launch_bounds__(256) void attn_kernel(
    const f16* __restrict__ Q, const f16* __restrict__ K,
    const f16* __restrict__ V, f16* __restrict__ O)
{
  __shared__ f16 lK[64 * 64];   // [key][d], swizzled 16B chunks
  __shared__ f16 lV[64 * 64];   // [d][key], swizzled 16B chunks
  const int tid = threadIdx.x;
  const int w = tid >> 6, lane = tid & 63, quad = lane >> 4, l16 = lane & 15;
  const int qt = blockIdx.x, bh = blockIdx.y;
  const f16* Qb = Q + (size_t)bh * SEQ * HD;
  const f16* Kb = K + (size_t)bh * SEQ * HD;
  const f16* Vb = V + (size_t)bh * HD * SEQ;
  const int q0 = qt * 64;
  const int qrow = q0 + w * 16 + l16;

  // Q B-frags (n = q = l16, k = d = quad*8+i), scale 1/sqrt(64) folded in
  h8v bq0 = *(const h8v*)&Qb[(size_t)qrow * HD + quad * 8];
  h8v bq1 = *(const h8v*)&Qb[(size_t)qrow * HD + quad * 8 + 32];
  bq0 = bq0 * (f16)0.125f;
  bq1 = bq1 * (f16)0.125f;

  // staging: chunk c -> row=c>>3, kc=(c&7)^(row&7)
  const int c0 = tid, c1 = 256 + tid;
  const int r0 = c0 >> 3, kc0 = (c0 & 7) ^ (r0 & 7);
  const int r1 = c1 >> 3, kc1 = (c1 & 7) ^ (r1 & 7);
  const f16* gK0 = Kb + (size_t)r0 * HD + kc0 * 8;
  const f16* gK1 = Kb + (size_t)r1 * HD + kc1 * 8;
  const f16* gV0 = Vb + (size_t)r0 * SEQ + kc0 * 8;
  const f16* gV1 = Vb + (size_t)r1 * SEQ + kc1 * 8;
  f16* lK0 = &lK[(c0 & ~63) * 8];
  f16* lK1 = &lK[(c1 & ~63) * 8];
  f16* lV0 = &lV[(c0 & ~63) * 8];
  f16* lV1 = &lV[(c1 & ~63) * 8];

  // K A-frag chunk idx: tile j (key row = j*16+l16), d-half kk
  int pbt[4][2];
#pragma unroll
  for (int j = 0; j < 4; ++j) {
    int r = j * 16 + l16;
#pragma unroll
    for (int kk = 0; kk < 2; ++kk)
      pbt[j][kk] = r * 8 + ((quad + 4 * kk) ^ (r & 7));
  }
  // V B-frag base (16x16x16): lane needs V[key=j*16+quad*4+i][d=dt*16+l16],
  // 8B from lV row d, key byte offset j*32+quad*8; dt adds 16 rows = 1024 f16
  const f16* vbase[4];
#pragma unroll
  for (int j = 0; j < 4; ++j) {
    int slot = (j * 2 + (quad >> 1)) ^ (l16 & 7);
    vbase[j] = &lV[l16 * 64 + slot * 8 + (quad & 1) * 4];
  }

  float mr = -1e30f, lr = 0.f;
  f4v accO[4] = {};

  for (int t = 0; t < SEQ / 64; ++t) {
    const int key0 = t * 64;
    __syncthreads();  // previous tile's reads done (all waves)
    gld16(gK0 + (size_t)key0 * HD, lK0);
    gld16(gK1 + (size_t)key0 * HD, lK1);
    gld16(gV0 + key0, lV0);
    gld16(gV1 + key0, lV1);
    __syncthreads();  // staged tile visible

    // S^T tile: sc[j] reg r = S[q=l16][key = j*16 + quad*4 + r]
    f4v sc[4];
#pragma unroll
    for (int j = 0; j < 4; ++j) {
      f4v z = {};
      z = mfma16(*(const h8v*)&lK[pbt[j][0] * 8], bq0, z);
      z = mfma16(*(const h8v*)&lK[pbt[j][1] * 8], bq1, z);
      sc[j] = z;
    }

    // in-lane max over the 16 held scores, then cross-quad
    float tm = sc[0][0];
#pragma unroll
    for (int j = 0; j < 4; ++j)
#pragma unroll
      for (int r = 0; r < 4; ++r) tm = fmaxf(tm, sc[j][r]);
    tm = fmaxf(tm, __shfl_xor(tm, 16, 64));
    tm = fmaxf(tm, __shfl_xor(tm, 32, 64));
    const float mnew = fmaxf(mr, tm);
    const float alpha = __expf(mr - mnew);
    mr = mnew;

    float p[4][4];
    float rs = 0.f;
#pragma unroll
    for (int j = 0; j < 4; ++j)
#pragma unroll
      for (int r = 0; r < 4; ++r) {
        p[j][r] = __expf(sc[j][r] - mnew);
        rs += p[j][r];
      }
    rs += __shfl_xor(rs, 16, 64);
    rs += __shfl_xor(rs, 32, 64);
    lr = lr * alpha + rs;

    // broadcast alpha from lane q=l16 to accO row q=quad*4+r
    f4v av;
#pragma unroll
    for (int r = 0; r < 4; ++r) av[r] = __shfl(alpha, quad * 4 + r, 64);
#pragma unroll
    for (int dt = 0; dt < 4; ++dt) accO[dt] *= av;

    // P is already in 16x16x16 A-frag layout
    h4v pf[4];
#pragma unroll
    for (int j = 0; j < 4; ++j)
      pf[j] = (h4v){(f16)p[j][0], (f16)p[j][1], (f16)p[j][2], (f16)p[j][3]};

#pragma unroll
    for (int dt = 0; dt < 4; ++dt)
#pragma unroll
      for (int j = 0; j < 4; ++j)
        accO[dt] = mfma16k16(pf[j], *(const h4v*)(vbase[j] + dt * 1024),
                             accO[dt]);
  }

  // normalize: 1/l broadcast to accO rows, then store O[q][d]
  f4v invl;
#pragma unroll
  for (int r = 0; r < 4; ++r) invl[r] = 1.0f / __shfl(lr, quad * 4 + r, 64);

  const int b = bh >> 4, hh = bh & 15;
#pragma unroll
  for (int dt = 0; dt < 4; ++dt) {
    const int d = dt * 16 + l16;
#pragma unroll
    for (int r = 0; r < 4; ++r) {
      const int s = q0 + w * 16 + quad * 4 + r;
      O[(size_t)(b * SEQ + s) * DIM + hh * HD + d] = (f16)(accO[dt][r] * invl[r]);
    }
  }
}

// ---------------------------------------------------------------- out GEMM
__global__ __launch_bounds__(256) void out_gemm(
    const f16* __restrict__ A, const f16* __restrict__ W,
    const float* __restrict__ bias, float* __restrict__ out)
{
  __shared__ f16 lA[64 * 32];
  __shared__ f16 lB[128 * 32];
  const int m0 = blockIdx.x * 64;
  const int n0 = blockIdx.y * 128;
  const int tid = threadIdx.x;
  const int w = tid >> 6, lane = tid & 63, quad = lane >> 4, l16 = lane & 15;
  const int wm = (w >> 1) * 32, wn = (w & 1) * 64;

  const int c0 = tid, c1 = 256 + tid;
  const int rA = c0 >> 2, kcA = (c0 & 3) ^ ((rA >> 1) & 3);
  const int rB1 = c1 >> 2, kcB1 = (c1 & 3) ^ ((rB1 >> 1) & 3);
  const f16* gA  = A + (size_t)(m0 + rA) * DIM + kcA * 8;
  const f16* gB0 = W + (size_t)(n0 + rA) * DIM + kcA * 8;
  const f16* gB1 = W + (size_t)(n0 + rB1) * DIM + kcB1 * 8;
  f16* lAp  = &lA[(c0 & ~63) * 8];
  f16* lB0p = &lB[(c0 & ~63) * 8];
  f16* lB1p = &lB[(c1 & ~63) * 8];

  int pA_[2], pB_[4];
#pragma unroll
  for (int t = 0; t < 2; ++t) {
    int r = wm + t * 16 + l16;
    pA_[t] = r * 4 + (quad ^ ((r >> 1) & 3));
  }
#pragma unroll
  for (int t = 0; t < 4; ++t) {
    int rn = wn + t * 16 + l16;
    pB_[t] = rn * 4 + (quad ^ ((rn >> 1) & 3));
  }

  f4v acc[2][4] = {};
  for (int kt = 0; kt < DIM / 32; ++kt) {
    const int ko = kt * 32;
    gld16(gA + ko, lAp);
    gld16(gB0 + ko, lB0p);
    gld16(gB1 + ko, lB1p);
    __syncthreads();
    h8v af[2], bf[4];
#pragma unroll
    for (int t = 0; t < 2; ++t) af[t] = *(const h8v*)&lA[pA_[t] * 8];
#pragma unroll
    for (int t = 0; t < 4; ++t) bf[t] = *(const h8v*)&lB[pB_[t] * 8];
#pragma unroll
    for (int i = 0; i < 2; ++i)
#pragma unroll
      for (int j = 0; j < 4; ++j)
        acc[i][j] = mfma16(af[i], bf[j], acc[i][j]);
    __syncthreads();
  }

#pragma unroll
  for (int i = 0; i < 2; ++i) {
#pragma unroll
    for (int j = 0; j < 4; ++j) {
      const int n = n0 + wn + j * 16 + l16;
      const float bv = bias[n];
#pragma unroll
      for (int r = 0; r < 4; ++r) {
        const int m = m0 + wm + i * 16 + quad * 4 + r;
        out[(size_t)m * DIM + n] = acc[i][j][r] + bv;
      }
    }
  }
}

// ------------------------------------------------------------------ launch
extern "C" void kernel_launch(void* const* d_in, const int* in_sizes, int n_in,
                              void* d_out, int out_size, void* d_ws, size_t ws_size,
                              hipStream_t stream)
{
  (void)in_sizes; (void)n_in; (void)out_size; (void)ws_size;
  const float* x  = (const float*)d_in[0];
  const float* Wq = (const float*)d_in[1];
  const float* Wk = (const float*)d_in[2];
  const float* Wv = (const float*)d_in[3];
  const float* Wo = (const float*)d_in[4];
  const float* bo = (const float*)d_in[5];
  float* out = (float*)d_out;

  char* ws = (char*)d_ws;
  const size_t MB = (size_t)1 << 20;
  f16* xh   = (f16*)(ws);             // 8 MB  [4096,1024]
  f16* wqkv = (f16*)(ws + 8  * MB);   // 6 MB  [3072,1024]
  f16* woh  = (f16*)(ws + 14 * MB);   // 2 MB  [1024,1024]
  f16* Qh   = (f16*)(ws + 16 * MB);   // 8 MB  [B,H,S,64]
  f16* Kh   = (f16*)(ws + 24 * MB);   // 8 MB  [B,H,S,64]
  f16* Vt   = (f16*)(ws + 32 * MB);   // 8 MB  [B,H,64,S]
  f16* Oh   = (f16*)(ws);             // 8 MB, reuses xh region

  convert_kernel<<<dim3(4096), 256, 0, stream>>>(x, Wq, Wk, Wv, Wo, xh, wqkv, woh);
  qkv_gemm<<<dim3(32, 24), 256, 0, stream>>>(xh, wqkv, Qh, Kh, Vt);
  attn_kernel<<<dim3(16, 64), 256, 0, stream>>>(Qh, Kh, Vt, Oh);
  out_gemm<<<dim3(64, 8), 256, 0, stream>>>(Oh, woh, bo, out);
}